// Round 1
// baseline (209.274 us; speedup 1.0000x reference)
//
#include <hip/hip_runtime.h>

namespace {

constexpr int LEN   = 160;
constexpr int PLANE = LEN * LEN;            // 25600
constexpr int VOL   = LEN * PLANE;          // 4,096,000 per batch
constexpr float INV_SZ = 1.0f / 125.0f;
constexpr float EPS_   = 1e-10f;

constexpr int TX = 32, TY = 32, ZC = 16;
constexpr int RX = TX + 4, RY = TY + 4;     // 36
constexpr int NRAW = RX * RY;               // 1296
constexpr int NCHZ = LEN / ZC;              // 10
constexpr int BLK  = 512;
constexpr int NXT  = RY * (TX / 4);         // 288 x-sum tasks per field

__device__ __forceinline__ int clampi(int v) {
  return v < 0 ? 0 : (v > LEN - 1 ? LEN - 1 : v);
}

// ---------------------------------------------------------------------------
// Two-field slab box3, software-pipelined, 2 barriers/plane.
// All LDS traffic vectorized: x-sums = 4-wide sliding tasks (2x ds_read_b128 +
// 1x ds_write_b128), y-sums/cen = ds_read_b64 via 2-consecutive-pixel
// ownership. Stride-36 rows => bank-uniform (row shifts banks by 4).
// MODE 0: outA = inA - box3(inA)/125 ; outB likewise.
// MODE 1: raw LDS holds unsquared values; x-sum squares on read.
//         outA = (inA/(sqrt(box3(inA^2)/125)+eps)) * (inB/(sqrt(box3(inB^2)/125)+eps))
// ---------------------------------------------------------------------------
template <int MODE>
__global__ __launch_bounds__(BLK) void slab2(const float* __restrict__ inA,
                                             const float* __restrict__ inB,
                                             float* __restrict__ outA,
                                             float* __restrict__ outB) {
  __shared__ __align__(16) float raw[2][RY][RX];   // 10.4 KB
  __shared__ __align__(16) float xs[2][RY][RX];    // 10.4 KB (cols 32..35 pad)

  const int tid = threadIdx.x;
  const int x0 = blockIdx.x * TX;
  const int y0 = blockIdx.y * TY;
  const int z0 = (blockIdx.z % NCHZ) * ZC;
  const size_t base = (size_t)(blockIdx.z / NCHZ) * VOL;

  // plane-invariant halo-load descriptors (3 predicated rounds)
  int off[3], lly[3], llx[3];
  bool act[3];
#pragma unroll
  for (int j = 0; j < 3; ++j) {
    int i = tid + j * BLK;
    act[j] = i < NRAW;
    int ii = act[j] ? i : 0;
    lly[j] = ii / RX; llx[j] = ii % RX;
    off[j] = clampi(y0 - 2 + lly[j]) * LEN + clampi(x0 - 2 + llx[j]);
  }

  // owned output pixels: 2 consecutive in x
  const int ly  = tid >> 4;           // 0..31
  const int lx0 = (tid & 15) * 2;     // 0,2,..,30

  float pfA[3], pfB[3];
  float2 rzA[5], rzB[5];              // z-ring of xy-sums
  float2 cenA[3], cenB[3];            // center-value ring, lag 2

  auto loadPlane = [&](int zp) {
    const size_t pb = base + (size_t)clampi(zp) * PLANE;
#pragma unroll
    for (int j = 0; j < 3; ++j)
      if (act[j]) { pfA[j] = inA[pb + off[j]]; pfB[j] = inB[pb + off[j]]; }
  };
  auto depositLDS = [&]() {
#pragma unroll
    for (int j = 0; j < 3; ++j)
      if (act[j]) { raw[0][lly[j]][llx[j]] = pfA[j]; raw[1][lly[j]][llx[j]] = pfB[j]; }
  };

  // 4-wide sliding x-sum task: t in [0, 2*NXT)
  auto xsumTask = [&](int t) {
    const int f = t & 1, c = (t >> 1) & 7, r = t >> 4;
    const float* rp = &raw[f][r][4 * c];
    float4 u = *(const float4*)rp;
    float4 v = *(const float4*)(rp + 4);
    if (MODE == 1) {
      u.x *= u.x; u.y *= u.y; u.z *= u.z; u.w *= u.w;
      v.x *= v.x; v.y *= v.y; v.z *= v.z; v.w *= v.w;
    }
    const float m = u.y + u.z + u.w;
    float4 s;
    s.x = m + u.x + v.x;          // a0..a4
    s.y = m + v.x + v.y;          // a1..a5
    s.z = s.y - u.y + v.z;        // a2..a6
    s.w = s.z - u.z + v.w;        // a3..a7
    *(float4*)&xs[f][r][4 * c] = s;
  };

  loadPlane(z0 - 2);
  depositLDS();
  __syncthreads();

  for (int zp = z0 - 2; zp <= z0 + ZC + 1; ++zp) {
    if (zp <= z0 + ZC) loadPlane(zp + 1);   // prefetch in flight during compute

    xsumTask(tid);
    if (tid < 2 * NXT - BLK) xsumTask(tid + BLK);   // 64 extra tasks

    // center stash (unsquared), ring shift: cen[0] ends up at lag 2
    cenA[0] = cenA[1]; cenA[1] = cenA[2];
    cenB[0] = cenB[1]; cenB[1] = cenB[2];
    cenA[2] = *(const float2*)&raw[0][ly + 2][lx0 + 2];
    cenB[2] = *(const float2*)&raw[1][ly + 2][lx0 + 2];

    __syncthreads();                        // xs ready; all raw reads done

    if (zp <= z0 + ZC) depositLDS();        // raw <- plane zp+1 (waits on prefetch)

    // y-sums into register z-ring
#pragma unroll
    for (int s = 0; s < 4; ++s) { rzA[s] = rzA[s + 1]; rzB[s] = rzB[s + 1]; }
    {
      float2 sa = {0.f, 0.f}, sb = {0.f, 0.f};
#pragma unroll
      for (int k = 0; k < 5; ++k) {
        const float2 a = *(const float2*)&xs[0][ly + k][lx0];
        const float2 b = *(const float2*)&xs[1][ly + k][lx0];
        sa.x += a.x; sa.y += a.y; sb.x += b.x; sb.y += b.y;
      }
      rzA[4] = sa; rzB[4] = sb;
    }

    if (zp >= z0 + 2) {
      const int zo = zp - 2;
      float2 bsA = {0.f, 0.f}, bsB = {0.f, 0.f};
#pragma unroll
      for (int s = 0; s < 5; ++s) {
        bsA.x += rzA[s].x; bsA.y += rzA[s].y;
        bsB.x += rzB[s].x; bsB.y += rzB[s].y;
      }
      const size_t g = base + (size_t)zo * PLANE + (size_t)(y0 + ly) * LEN + (x0 + lx0);
      if (MODE == 0) {
        float2 oa, ob;
        oa.x = cenA[0].x - bsA.x * INV_SZ; oa.y = cenA[0].y - bsA.y * INV_SZ;
        ob.x = cenB[0].x - bsB.x * INV_SZ; ob.y = cenB[0].y - bsB.y * INV_SZ;
        *(float2*)&outA[g] = oa;
        *(float2*)&outB[g] = ob;
      } else {
        float2 o;
        o.x = (cenA[0].x / (sqrtf(bsA.x * INV_SZ) + EPS_)) *
              (cenB[0].x / (sqrtf(bsB.x * INV_SZ) + EPS_));
        o.y = (cenA[0].y / (sqrtf(bsA.y * INV_SZ) + EPS_)) *
              (cenB[0].y / (sqrtf(bsB.y * INV_SZ) + EPS_));
        *(float2*)&outA[g] = o;
      }
    }
    __syncthreads();                        // raw(zp+1) ready; xs reads done
  }
}

// ---------------------------------------------------------------------------
// Stage C: cross = box3(p); acc += cross^2 * mask; block reduce -> atomicAdd.
// Same vectorized LDS scheme, single field.
// ---------------------------------------------------------------------------
__global__ __launch_bounds__(BLK) void slab1_reduce(const float* __restrict__ p,
                                                    const float* __restrict__ mask,
                                                    float* __restrict__ out) {
  __shared__ __align__(16) float raw[RY][RX];
  __shared__ __align__(16) float xs[RY][RX];
  __shared__ float wsum[BLK / 64];

  const int tid = threadIdx.x;
  const int x0 = blockIdx.x * TX;
  const int y0 = blockIdx.y * TY;
  const int z0 = (blockIdx.z % NCHZ) * ZC;
  const size_t base = (size_t)(blockIdx.z / NCHZ) * VOL;

  int off[3], lly[3], llx[3];
  bool act[3];
#pragma unroll
  for (int j = 0; j < 3; ++j) {
    int i = tid + j * BLK;
    act[j] = i < NRAW;
    int ii = act[j] ? i : 0;
    lly[j] = ii / RX; llx[j] = ii % RX;
    off[j] = clampi(y0 - 2 + lly[j]) * LEN + clampi(x0 - 2 + llx[j]);
  }
  const int ly  = tid >> 4;
  const int lx0 = (tid & 15) * 2;

  float pf[3];
  float2 rz[5];
  float acc = 0.f;

  auto loadPlane = [&](int zp) {
    const size_t pb = base + (size_t)clampi(zp) * PLANE;
#pragma unroll
    for (int j = 0; j < 3; ++j)
      if (act[j]) pf[j] = p[pb + off[j]];
  };
  auto depositLDS = [&]() {
#pragma unroll
    for (int j = 0; j < 3; ++j)
      if (act[j]) raw[lly[j]][llx[j]] = pf[j];
  };

  loadPlane(z0 - 2);
  depositLDS();
  __syncthreads();

  for (int zp = z0 - 2; zp <= z0 + ZC + 1; ++zp) {
    if (zp <= z0 + ZC) loadPlane(zp + 1);

    if (tid < NXT) {                        // 288 x-sum tasks
      const int c = tid & 7, r = tid >> 3;
      const float* rp = &raw[r][4 * c];
      const float4 u = *(const float4*)rp;
      const float4 v = *(const float4*)(rp + 4);
      const float m = u.y + u.z + u.w;
      float4 s;
      s.x = m + u.x + v.x;
      s.y = m + v.x + v.y;
      s.z = s.y - u.y + v.z;
      s.w = s.z - u.z + v.w;
      *(float4*)&xs[r][4 * c] = s;
    }
    __syncthreads();

    if (zp <= z0 + ZC) depositLDS();

#pragma unroll
    for (int s = 0; s < 4; ++s) rz[s] = rz[s + 1];
    {
      float2 s2 = {0.f, 0.f};
#pragma unroll
      for (int k = 0; k < 5; ++k) {
        const float2 a = *(const float2*)&xs[ly + k][lx0];
        s2.x += a.x; s2.y += a.y;
      }
      rz[4] = s2;
    }

    if (zp >= z0 + 2) {
      const int zo = zp - 2;
      float2 bs = {0.f, 0.f};
#pragma unroll
      for (int s = 0; s < 5; ++s) { bs.x += rz[s].x; bs.y += rz[s].y; }
      const size_t g = base + (size_t)zo * PLANE + (size_t)(y0 + ly) * LEN + (x0 + lx0);
      const float2 mk = *(const float2*)&mask[g];
      acc += bs.x * bs.x * mk.x + bs.y * bs.y * mk.y;
    }
    __syncthreads();
  }

#pragma unroll
  for (int o = 32; o > 0; o >>= 1) acc += __shfl_down(acc, o, 64);
  const int lane = tid & 63, wid = tid >> 6;
  if (lane == 0) wsum[wid] = acc;
  __syncthreads();
  if (tid == 0) {
    float t = 0.f;
#pragma unroll
    for (int w = 0; w < BLK / 64; ++w) t += wsum[w];
    atomicAdd(out, -t);
  }
}

}  // namespace

extern "C" void kernel_launch(void* const* d_in, const int* in_sizes, int n_in,
                              void* d_out, int out_size, void* d_ws, size_t ws_size,
                              hipStream_t stream) {
  const float* F    = (const float*)d_in[0];
  const float* M    = (const float*)d_in[1];
  const float* mask = (const float*)d_in[2];
  float* out = (float*)d_out;

  const size_t bufB = (size_t)(2 * VOL) * sizeof(float);
  char* ws = (char*)d_ws;
  float* dF = (float*)ws;
  float* dM = (float*)(ws + bufB);
  float* pB = (float*)(ws + 2 * bufB);

  hipMemsetAsync(d_out, 0, sizeof(float), stream);

  dim3 grd(LEN / TX, LEN / TY, NCHZ * 2), blk(BLK);

  slab2<0><<<grd, blk, 0, stream>>>(F, M, dF, dM);
  slab2<1><<<grd, blk, 0, stream>>>(dF, dM, pB, nullptr);
  slab1_reduce<<<grd, blk, 0, stream>>>(pB, mask, out);
}